// Round 2
// baseline (156.427 us; speedup 1.0000x reference)
//
#include <hip/hip_runtime.h>

// VP_lattice reverse step, B = 2^20 rows.
// SVD+einsum in the reference == sqrtm(A^T A) (symmetric polar factor),
// computed closed-form (Franca/Cayley-Hamilton). Round-2 changes:
//  - fp64 only for cancellation-prone algebra (invariants, CH solve);
//    the trig cos(acos(x)/3) runs in fp32 (error <=~1e-4 at the arg=-1
//    corner -> U error ~3e-4, abs budget is ~7e-3).
//  - branchless near-spherical handling (formula degrades gracefully).
//  - 2 rows/thread: two independent dependency chains per wave (this kernel
//    is latency-bound: R1 measured VALUBusy 28% = pure issue time, rest is
//    serial fp64 chain latency) + float4 loads for lt/pl0/z/out.

#define NUM_STEPS 1000

__global__ __launch_bounds__(256) void vp_lattice_kernel(
    const float* __restrict__ lt,
    const float* __restrict__ pl0,
    const float* __restrict__ plat,
    const float* __restrict__ alpha_bars,
    const float* __restrict__ betas,
    const float* __restrict__ sigmas,
    const float* __restrict__ z_noise,
    const int*   __restrict__ t,
    float* __restrict__ out,
    int npair)
{
    int gid = blockIdx.x * blockDim.x + threadIdx.x;
    if (gid >= npair) return;

    // ---- vector loads: 2 consecutive rows per thread ----
    // lt/pl0/z rows: 2 rows = 12 floats = 48B, offset gid*48 -> 16-aligned.
    const float4* ltp = reinterpret_cast<const float4*>(lt)      + (size_t)gid * 3;
    const float4* plp = reinterpret_cast<const float4*>(pl0)     + (size_t)gid * 3;
    const float4* znp = reinterpret_cast<const float4*>(z_noise) + (size_t)gid * 3;
    float4 l4a = ltp[0], l4b = ltp[1], l4c = ltp[2];
    float4 p4a = plp[0], p4b = plp[1], p4c = plp[2];
    float4 z4a = znp[0], z4b = znp[1], z4c = znp[2];

    // plat: 2 rows = 18 floats = 72B, offset gid*72 -> 8-aligned -> float2 x9.
    const float2* pp = reinterpret_cast<const float2*>(plat) + (size_t)gid * 9;
    float a[18];
#pragma unroll
    for (int j = 0; j < 9; ++j) { float2 w = pp[j]; a[2*j] = w.x; a[2*j+1] = w.y; }

    int2 tt = reinterpret_cast<const int2*>(t)[gid];
    float beta_last = betas[NUM_STEPS - 1];   // betas[-2]

    float vv[12];
#pragma unroll
    for (int r = 0; r < 2; ++r) {
        const float* A = a + r * 9;
        double a00 = A[0], a01 = A[1], a02 = A[2];
        double a10 = A[3], a11 = A[4], a12 = A[5];
        double a20 = A[6], a21 = A[7], a22 = A[8];

        // M = A^T A (symmetric PSD)
        double m00 = a00*a00 + a10*a10 + a20*a20;
        double m01 = a00*a01 + a10*a11 + a20*a21;
        double m02 = a00*a02 + a10*a12 + a20*a22;
        double m11 = a01*a01 + a11*a11 + a21*a21;
        double m12 = a01*a02 + a11*a12 + a21*a22;
        double m22 = a02*a02 + a12*a12 + a22*a22;

        // invariants (fp64: k and l suffer cancellation)
        double I1   = m00 + m11 + m22;
        double trM2 = m00*m00 + m11*m11 + m22*m22
                    + 2.0*(m01*m01 + m02*m02 + m12*m12);
        double II   = 0.5*(I1*I1 - trM2);
        double III  = m00*(m11*m22 - m12*m12)
                    - m01*(m01*m22 - m12*m02)
                    + m02*(m01*m12 - m11*m02);
        double k = I1*I1 - 3.0*II;                  // >= 0
        double l = I1*(I1*I1 - 4.5*II) + 13.5*III;
        double sqk = sqrt(fmax(k, 0.0));

        // trig in fp32: c = cos(acos(arg)/3). mu1 is insensitive to c when
        // sqk is small, and |dc/darg| blowup at arg->-1 costs <= ~1e-4 in c.
        float denf = fmaxf((float)(k * sqk), 1e-30f);
        float argf = fminf(fmaxf((float)l / denf, -1.0f), 1.0f);
        float cf   = cosf(acosf(argf) * (1.0f/3.0f));

        double mu1  = fmax((I1 + 2.0*sqk*(double)cf) * (1.0/3.0), 0.0);
        double lam1 = sqrt(mu1);                    // largest singular value
        double sqIII = sqrt(fmax(III, 0.0));
        double rest = I1 - mu1 + 2.0*sqIII / fmax(lam1, 1e-150);
        double s23  = sqrt(fmax(rest, 0.0));        // lam2 + lam3
        double IU   = lam1 + s23;                   // tr(U)
        double IIU  = 0.5*(IU*IU - I1);             // since tr(U^2) = I1
        double IIIU = sqIII;                        // det(U)

        // Cayley-Hamilton: (M + IIU*Id) U = IU*M + IIIU*Id
        double p00 = m00 + IIU, p11 = m11 + IIU, p22 = m22 + IIU;
        double c00 = p11*p22 - m12*m12;
        double c01 = m02*m12 - m01*p22;
        double c02 = m01*m12 - p11*m02;
        double c11 = p00*p22 - m02*m02;
        double c12 = m01*m02 - p00*m12;
        double c22 = p00*p11 - m01*m01;
        double detP = p00*c00 + m01*c01 + m02*c02;  // > 0 (P is PD)
        double inv  = 1.0 / fmax(detP, 1e-280);
        double n00 = IU*m00 + IIIU, n01 = IU*m01, n02 = IU*m02;
        double n11 = IU*m11 + IIIU, n12 = IU*m12, n22 = IU*m22 + IIIU;
        double u00 = (c00*n00 + c01*n01 + c02*n02) * inv;
        double u11 = (c01*n01 + c11*n11 + c12*n12) * inv;
        double u22 = (c02*n02 + c12*n12 + c22*n22) * inv;
        double u01 = 0.5*((c00*n01 + c01*n11 + c02*n12) +
                          (c01*n00 + c11*n01 + c12*n02)) * inv;
        double u02 = 0.5*((c00*n02 + c01*n12 + c02*n22) +
                          (c02*n00 + c12*n01 + c22*n02)) * inv;
        double u12 = 0.5*((c01*n02 + c11*n12 + c12*n22) +
                          (c02*n01 + c12*n11 + c22*n12)) * inv;

        vv[r*6 + 0] = (float)u00; vv[r*6 + 1] = (float)u01;
        vv[r*6 + 2] = (float)u02; vv[r*6 + 3] = (float)u11;
        vv[r*6 + 4] = (float)u12; vv[r*6 + 5] = (float)u22;
    }

    // ---- schedule + elementwise epilogue (fp32) ----
    float lv[12] = {l4a.x, l4a.y, l4a.z, l4a.w, l4b.x, l4b.y,
                    l4b.z, l4b.w, l4c.x, l4c.y, l4c.z, l4c.w};
    float pv[12] = {p4a.x, p4a.y, p4a.z, p4a.w, p4b.x, p4b.y,
                    p4b.z, p4b.w, p4c.x, p4c.y, p4c.z, p4c.w};
    float zv[12] = {z4a.x, z4a.y, z4a.z, z4a.w, z4b.x, z4b.y,
                    z4b.z, z4b.w, z4c.x, z4c.y, z4c.z, z4c.w};
    float ov[12];

#pragma unroll
    for (int r = 0; r < 2; ++r) {
        int ti = (r == 0) ? tt.x : tt.y;
        float alpha = 1.0f - fminf(betas[ti], beta_last);
        float ab    = alpha_bars[ti];
        float sig   = sigmas[ti];
        float coef  = 1.0f / sqrtf(alpha + 1e-8f);
        float scale = (1.0f - alpha) / sqrtf(1.0f - ab + 1e-8f);
        float zgate = (ti > 1) ? 1.0f : 0.0f;
#pragma unroll
        for (int c = 0; c < 6; ++c) {
            float lc = lv[r*6 + c];
            float pn = lc - 0.5f * (vv[r*6 + c] + pv[r*6 + c]);
            ov[r*6 + c] = coef * (lc - scale * pn) + sig * (zgate * zv[r*6 + c]);
        }
    }

    float4* op = reinterpret_cast<float4*>(out) + (size_t)gid * 3;
    op[0] = make_float4(ov[0], ov[1], ov[2],  ov[3]);
    op[1] = make_float4(ov[4], ov[5], ov[6],  ov[7]);
    op[2] = make_float4(ov[8], ov[9], ov[10], ov[11]);
}

extern "C" void kernel_launch(void* const* d_in, const int* in_sizes, int n_in,
                              void* d_out, int out_size, void* d_ws, size_t ws_size,
                              hipStream_t stream) {
    const float* lt         = (const float*)d_in[0];
    const float* pl0        = (const float*)d_in[1];
    const float* plat       = (const float*)d_in[2];
    const float* alpha_bars = (const float*)d_in[3];
    const float* betas      = (const float*)d_in[4];
    const float* sigmas     = (const float*)d_in[5];
    const float* z_noise    = (const float*)d_in[6];
    const int*   t          = (const int*)d_in[7];
    float* out = (float*)d_out;

    int n = in_sizes[0] / 6;        // B rows (even: 2^20)
    int npair = n / 2;              // 2 rows per thread
    int block = 256;
    int grid = (npair + block - 1) / block;
    vp_lattice_kernel<<<grid, block, 0, stream>>>(
        lt, pl0, plat, alpha_bars, betas, sigmas, z_noise, t, out, npair);
}

// Round 3
// 153.613 us; speedup vs baseline: 1.0183x; 1.0183x over previous
//
#include <hip/hip_runtime.h>

// VP_lattice reverse step, B = 2^20 rows. Round-3:
//  - SVD+einsum == sqrtm(A^T A); all-fp32 via cancellation-free trig
//    eigenvalues (dsyevc3 form) + Hoger-Carlson inverse-free sqrtm formula.
//  - Schedule tables: per-lane divergent VMEM gathers (R1/R2's hidden
//    bottleneck: TA/L1 serialization, tables evicted by streaming) replaced
//    by LDS-cached precomputed {coef, scale, sig*gate} per timestep.
//  - 1 row/thread, float2 loads (R1 layout: best measured occupancy).

#define NUM_STEPS 1000

__global__ __launch_bounds__(256) void vp_lattice_kernel(
    const float* __restrict__ lt,
    const float* __restrict__ pl0,
    const float* __restrict__ plat,
    const float* __restrict__ alpha_bars,
    const float* __restrict__ betas,
    const float* __restrict__ sigmas,
    const float* __restrict__ z_noise,
    const int*   __restrict__ t,
    float* __restrict__ out,
    int n)
{
    // ---- LDS schedule: coef, scale, sig*gate per timestep (12 KB) ----
    __shared__ float sCoef[NUM_STEPS + 1];
    __shared__ float sScale[NUM_STEPS + 1];
    __shared__ float sSig[NUM_STEPS + 1];
    {
        float beta_last = betas[NUM_STEPS - 1];          // betas[-2]
        for (int j = threadIdx.x; j <= NUM_STEPS; j += 256) {
            float alpha = 1.0f - fminf(betas[j], beta_last);
            sCoef[j]  = 1.0f / sqrtf(alpha + 1e-8f);
            sScale[j] = (1.0f - alpha) / sqrtf(1.0f - alpha_bars[j] + 1e-8f);
            sSig[j]   = (j > 1) ? sigmas[j] : 0.0f;
        }
    }
    __syncthreads();

    int i = blockIdx.x * blockDim.x + threadIdx.x;
    if (i >= n) return;

    // ---- load A (3x3 row-major), 9 floats ----
    size_t b9 = (size_t)i * 9;
    float a00 = plat[b9+0], a01 = plat[b9+1], a02 = plat[b9+2];
    float a10 = plat[b9+3], a11 = plat[b9+4], a12 = plat[b9+5];
    float a20 = plat[b9+6], a21 = plat[b9+7], a22 = plat[b9+8];

    // ---- M = A^T A (symmetric PSD) ----
    float m00 = a00*a00 + a10*a10 + a20*a20;
    float m01 = a00*a01 + a10*a11 + a20*a21;
    float m02 = a00*a02 + a10*a12 + a20*a22;
    float m11 = a01*a01 + a11*a11 + a21*a21;
    float m12 = a01*a02 + a11*a12 + a21*a22;
    float m22 = a02*a02 + a12*a12 + a22*a22;

    // ---- eigenvalues: cancellation-free trig form ----
    float q  = (m00 + m11 + m22) * (1.0f/3.0f);
    float b00 = m00 - q, b11 = m11 - q, b22 = m22 - q;
    float p1 = m01*m01 + m02*m02 + m12*m12;
    float p2 = b00*b00 + b11*b11 + b22*b22 + 2.0f*p1;   // = (2/3) k
    float p  = sqrtf(p2 * (1.0f/6.0f));
    float detB = b00*(b11*b22 - m12*m12)
               - m01*(m01*b22 - m12*m02)
               + m02*(m01*m12 - b11*m02);
    float pinv = 1.0f / fmaxf(p, 1e-20f);
    float r = 0.5f * detB * pinv * pinv * pinv;
    r = fminf(fmaxf(r, -1.0f), 1.0f);
    float phi = acosf(r) * (1.0f/3.0f);                  // [0, pi/3]
    float mu1 = q + 2.0f*p*cosf(phi);                    // largest
    float mu3 = q + 2.0f*p*cosf(phi + 2.0943951023931953f); // smallest
    float mu2 = 3.0f*q - mu1 - mu3;
    float l1 = sqrtf(fmaxf(mu1, 0.0f));
    float l2 = sqrtf(fmaxf(mu2, 0.0f));
    float l3 = sqrtf(fmaxf(mu3, 0.0f));

    // ---- U = sqrtm(M), Hoger-Carlson (inverse-free) ----
    // U = (-M^2 + (IU^2-IIU) M + IU*IIIU*Id) / ((l1+l2)(l1+l3)(l2+l3))
    float IU   = l1 + l2 + l3;
    float IIU  = l1*(l2 + l3) + l2*l3;
    float IIIU = l1*l2*l3;
    float denom = (l1 + l2) * (l1 + l3) * (l2 + l3);
    float dinv  = 1.0f / fmaxf(denom, 1e-25f);
    float sd = (IU*IU - IIU) * dinv;      // coefficient of M
    float td = IU * IIIU * dinv;          // coefficient of Id
    float nd = -dinv;                     // coefficient of M^2

    float mm00 = m00*m00 + m01*m01 + m02*m02;
    float mm01 = m00*m01 + m01*m11 + m02*m12;
    float mm02 = m00*m02 + m01*m12 + m02*m22;
    float mm11 = m01*m01 + m11*m11 + m12*m12;
    float mm12 = m01*m02 + m11*m12 + m12*m22;
    float mm22 = m02*m02 + m12*m12 + m22*m22;

    float v0 = nd*mm00 + sd*m00 + td;     // L00
    float v1 = nd*mm01 + sd*m01;          // L01
    float v2 = nd*mm02 + sd*m02;          // L02
    float v3 = nd*mm11 + sd*m11 + td;     // L11
    float v4 = nd*mm12 + sd*m12;          // L12
    float v5 = nd*mm22 + sd*m22 + td;     // L22

    // ---- schedule from LDS ----
    int ti = t[i];
    float coef  = sCoef[ti];
    float scale = sScale[ti];
    float sig   = sSig[ti];

    // ---- elementwise epilogue, float2 (rows are 8-aligned: 6 floats) ----
    size_t b6 = (size_t)i * 6;
    const float2* lt2 = reinterpret_cast<const float2*>(lt + b6);
    const float2* p02 = reinterpret_cast<const float2*>(pl0 + b6);
    const float2* zn2 = reinterpret_cast<const float2*>(z_noise + b6);
    float2* out2      = reinterpret_cast<float2*>(out + b6);

    float lv[6], pv[6], zv[6];
    float2 w;
    w = lt2[0]; lv[0]=w.x; lv[1]=w.y;
    w = lt2[1]; lv[2]=w.x; lv[3]=w.y;
    w = lt2[2]; lv[4]=w.x; lv[5]=w.y;
    w = p02[0]; pv[0]=w.x; pv[1]=w.y;
    w = p02[1]; pv[2]=w.x; pv[3]=w.y;
    w = p02[2]; pv[4]=w.x; pv[5]=w.y;
    w = zn2[0]; zv[0]=w.x; zv[1]=w.y;
    w = zn2[1]; zv[2]=w.x; zv[3]=w.y;
    w = zn2[2]; zv[4]=w.x; zv[5]=w.y;

    float vv[6] = {v0, v1, v2, v3, v4, v5};
    float ov[6];
#pragma unroll
    for (int c = 0; c < 6; ++c) {
        float lc = lv[c];
        float pn = lc - 0.5f * (vv[c] + pv[c]);          // predicted_noise
        ov[c] = coef * (lc - scale * pn) + sig * zv[c];
    }
    out2[0] = make_float2(ov[0], ov[1]);
    out2[1] = make_float2(ov[2], ov[3]);
    out2[2] = make_float2(ov[4], ov[5]);
}

extern "C" void kernel_launch(void* const* d_in, const int* in_sizes, int n_in,
                              void* d_out, int out_size, void* d_ws, size_t ws_size,
                              hipStream_t stream) {
    const float* lt         = (const float*)d_in[0];
    const float* pl0        = (const float*)d_in[1];
    const float* plat       = (const float*)d_in[2];
    const float* alpha_bars = (const float*)d_in[3];
    const float* betas      = (const float*)d_in[4];
    const float* sigmas     = (const float*)d_in[5];
    const float* z_noise    = (const float*)d_in[6];
    const int*   t          = (const int*)d_in[7];
    float* out = (float*)d_out;

    int n = in_sizes[0] / 6;   // B rows
    int block = 256;
    int grid = (n + block - 1) / block;
    vp_lattice_kernel<<<grid, block, 0, stream>>>(
        lt, pl0, plat, alpha_bars, betas, sigmas, z_noise, t, out, n);
}